// Round 1
// baseline (130.767 us; speedup 1.0000x reference)
//
#include <hip/hip_runtime.h>
#include <hip/hip_bf16.h>

#define NROWS 16384
#define DDIM  256
#define LOG2E 1.4426950408889634f
#define SCALE 7.213475204444817f   // (1/tau) * log2(e), tau = 0.2

typedef __attribute__((ext_vector_type(8))) short short8;
typedef __attribute__((ext_vector_type(4))) float f32x4;

__device__ __forceinline__ unsigned short f2bf_rne(float f) {
  union { float f; unsigned int u; } v; v.f = f;
  unsigned int u = v.u;
  return (unsigned short)((u + 0x7FFFu + ((u >> 16) & 1u)) >> 16);
}

// ---------------------------------------------------------------------------
// Kernel 1: L2-normalize rows of z1,z2 -> bf16 h1,h2; exact fp32 diag logits
// (diag5[i] = 5 * cos(z1_i, z2_i)); zero rowsum. One wave per row.
// ---------------------------------------------------------------------------
__global__ __launch_bounds__(256) void prep_kernel(
    const float* __restrict__ z1, const float* __restrict__ z2,
    ushort* __restrict__ h1, ushort* __restrict__ h2,
    float* __restrict__ diag5, float* __restrict__ rowsum) {
  int tid = threadIdx.x;
  int w = tid >> 6, lane = tid & 63;
  int r = blockIdx.x * 4 + w;

  const float4 a = ((const float4*)z1)[r * 64 + lane];
  const float4 b = ((const float4*)z2)[r * 64 + lane];

  float ss1 = a.x * a.x + a.y * a.y + a.z * a.z + a.w * a.w;
  float ss2 = b.x * b.x + b.y * b.y + b.z * b.z + b.w * b.w;
  float dp  = a.x * b.x + a.y * b.y + a.z * b.z + a.w * b.w;
  #pragma unroll
  for (int m = 1; m <= 32; m <<= 1) {
    ss1 += __shfl_xor(ss1, m);
    ss2 += __shfl_xor(ss2, m);
    dp  += __shfl_xor(dp, m);
  }
  float inv1 = 1.0f / fmaxf(sqrtf(ss1), 1e-12f);
  float inv2 = 1.0f / fmaxf(sqrtf(ss2), 1e-12f);

  ushort4 o1, o2;
  o1.x = f2bf_rne(a.x * inv1); o1.y = f2bf_rne(a.y * inv1);
  o1.z = f2bf_rne(a.z * inv1); o1.w = f2bf_rne(a.w * inv1);
  o2.x = f2bf_rne(b.x * inv2); o2.y = f2bf_rne(b.y * inv2);
  o2.z = f2bf_rne(b.z * inv2); o2.w = f2bf_rne(b.w * inv2);
  ((ushort4*)h1)[r * 64 + lane] = o1;
  ((ushort4*)h2)[r * 64 + lane] = o2;

  if (lane == 0) diag5[r] = dp * inv1 * inv2 * 5.0f;
  if (tid < 4) rowsum[blockIdx.x * 4 + tid] = 0.0f;  // 4096 blocks * 4 = 16384
}

// ---------------------------------------------------------------------------
// Kernel 2: rowsum_i = sum_j exp(sim_ij / tau) via bf16 MFMA.
// Block = 512 thr (8 waves). BM=512 rows/block, 8-way column split ->
// grid = 32*8 = 256 blocks. Each wave owns 64 rows; A fragments live in
// registers for the whole kernel. h2 tiles (64 cols x 256 k) double-buffered
// in LDS via global_load_lds(width=16) with XOR-swizzled SOURCE (linear LDS
// dest) and the same XOR on the read side -> conflict-free ds_read_b128.
// ---------------------------------------------------------------------------
#define CSPL 8
#define BN   64
#define NJT  ((NROWS / CSPL) / BN)   // 32 j-tiles per block

__global__ __launch_bounds__(512, 2) void simexp_kernel(
    const ushort* __restrict__ h1, const ushort* __restrict__ h2,
    float* __restrict__ rowsum) {
  __shared__ alignas(16) ushort lds[2][BN * DDIM];   // 2 x 32 KB

  int tid = threadIdx.x, w = tid >> 6, lane = tid & 63;
  int bx = blockIdx.x;
  int rb = bx >> 3;       // row block 0..31
  int cs = bx & 7;        // column split 0..7 == default XCD id (L2 locality)
  int row0 = rb * 512 + w * 64;
  int c0 = cs * (NROWS / CSPL);

  const char* h1b = (const char*)h1;
  const char* h2b = (const char*)h2;

  // A fragments: 4 row-subtiles x 8 k-steps, 8 bf16 each -> 128 VGPRs
  short8 afr[4][8];
  #pragma unroll
  for (int m = 0; m < 4; ++m)
    #pragma unroll
    for (int ks = 0; ks < 8; ++ks) {
      int row = row0 + m * 16 + (lane & 15);
      int off = row * 512 + ks * 64 + (lane >> 4) * 16;
      afr[m][ks] = *reinterpret_cast<const short8*>(h1b + off);
    }

  float rs[4][4];
  #pragma unroll
  for (int m = 0; m < 4; ++m)
    #pragma unroll
    for (int r = 0; r < 4; ++r) rs[m][r] = 0.0f;

  // stage one 64x256 bf16 h2 tile: wave w stages rows w*8..w*8+7 (4 instrs)
  auto stage = [&](int buf, int jt) {
    int j0 = c0 + jt * BN;
    int rbase = w * 8;
    #pragma unroll
    for (int i = 0; i < 4; ++i) {
      int rit = rbase + i * 2 + (lane >> 5);         // row in tile 0..63
      int kb  = (lane & 31) * 16;                    // byte offset in row
      int src = (j0 + rit) * 512 + (kb ^ ((rit & 7) << 4));  // pre-swizzled src
      __builtin_amdgcn_global_load_lds(
          (const __attribute__((address_space(1))) void*)(h2b + src),
          (__attribute__((address_space(3))) void*)&lds[buf][(rbase + i * 2) * DDIM],
          16, 0, 0);
    }
  };

  stage(0, 0);
  __syncthreads();

  for (int jt = 0; jt < NJT; ++jt) {
    int cur = jt & 1;
    if (jt + 1 < NJT) stage(cur ^ 1, jt + 1);

    const char* L = (const char*)lds[cur];
    #pragma unroll
    for (int n = 0; n < 4; ++n) {
      f32x4 acc[4];
      #pragma unroll
      for (int m = 0; m < 4; ++m) acc[m] = (f32x4){0.f, 0.f, 0.f, 0.f};

      #pragma unroll
      for (int ks = 0; ks < 8; ++ks) {
        int row = n * 16 + (lane & 15);
        int kb  = ks * 64 + (lane >> 4) * 16;
        int off = row * 512 + (kb ^ ((row & 7) << 4));   // same involution as stage
        short8 bfr = *reinterpret_cast<const short8*>(L + off);
        #pragma unroll
        for (int m = 0; m < 4; ++m)
          acc[m] = __builtin_amdgcn_mfma_f32_16x16x32_bf16(afr[m][ks], bfr, acc[m], 0, 0, 0);
      }
      // exp(sim/tau) = exp2(sim * SCALE); accumulate row partial sums
      #pragma unroll
      for (int m = 0; m < 4; ++m)
        #pragma unroll
        for (int r = 0; r < 4; ++r)
          rs[m][r] += __builtin_amdgcn_exp2f(acc[m][r] * SCALE);
    }
    __syncthreads();
  }

  // reduce the 16 column-lanes (lane&15) and add to global rowsum
  #pragma unroll
  for (int m = 0; m < 4; ++m)
    #pragma unroll
    for (int r = 0; r < 4; ++r) {
      float v = rs[m][r];
      v += __shfl_xor(v, 1);
      v += __shfl_xor(v, 2);
      v += __shfl_xor(v, 4);
      v += __shfl_xor(v, 8);
      if ((lane & 15) == 0)
        atomicAdd(&rowsum[row0 + m * 16 + (lane >> 4) * 4 + r], v);
    }
}

// ---------------------------------------------------------------------------
// Kernel 3: loss = sum_i [ log(rowsum_i - exp(diag5_i)) - diag5_i ]
// ---------------------------------------------------------------------------
__global__ __launch_bounds__(1024) void loss_kernel(
    const float* __restrict__ rowsum, const float* __restrict__ diag5,
    float* __restrict__ out) {
  int tid = threadIdx.x;
  float s = 0.0f;
  for (int i = tid; i < NROWS; i += 1024) {
    float d5 = diag5[i];
    float de = __builtin_amdgcn_exp2f(d5 * LOG2E);
    s += logf(rowsum[i] - de) - d5;
  }
  #pragma unroll
  for (int m = 1; m <= 32; m <<= 1) s += __shfl_xor(s, m);
  __shared__ float wsum[16];
  if ((tid & 63) == 0) wsum[tid >> 6] = s;
  __syncthreads();
  if (tid == 0) {
    float t = 0.0f;
    #pragma unroll
    for (int i = 0; i < 16; ++i) t += wsum[i];
    out[0] = t;
  }
}

// ---------------------------------------------------------------------------
extern "C" void kernel_launch(void* const* d_in, const int* in_sizes, int n_in,
                              void* d_out, int out_size, void* d_ws, size_t ws_size,
                              hipStream_t stream) {
  const float* z1 = (const float*)d_in[0];
  const float* z2 = (const float*)d_in[1];

  char* ws = (char*)d_ws;
  ushort* h1    = (ushort*)(ws);               // 16384*256*2 = 8388608 B
  ushort* h2    = (ushort*)(ws + 8388608);     // 8388608 B
  float*  diag5 = (float*)(ws + 16777216);     // 65536 B
  float*  rowsm = (float*)(ws + 16842752);     // 65536 B
  if (ws_size < 16908288) return;              // fail loudly (poison stays)

  prep_kernel<<<4096, 256, 0, stream>>>(z1, z2, h1, h2, diag5, rowsm);
  simexp_kernel<<<256, 512, 0, stream>>>(h1, h2, rowsm);
  loss_kernel<<<1, 1024, 0, stream>>>(rowsm, diag5, (float*)d_out);
}